// Round 6
// baseline (528.691 us; speedup 1.0000x reference)
//
#include <hip/hip_runtime.h>
#include <stdint.h>

typedef __attribute__((ext_vector_type(8))) short short8;
typedef __attribute__((ext_vector_type(4))) float floatx4;

__device__ inline unsigned short f2bf(float f){
  union { float fv; unsigned int u; } v; v.fv = f;
  unsigned int u = v.u;
  unsigned int r = ((u >> 16) & 1u) + 0x7FFFu;
  return (unsigned short)((u + r) >> 16);
}

// async global->LDS, 16B per lane, dest = wave-uniform base + lane*16
__device__ __forceinline__ void async16(const void* g, void* l){
  __builtin_amdgcn_global_load_lds(
      (const __attribute__((address_space(1))) unsigned int*)g,
      (__attribute__((address_space(3))) unsigned int*)l, 16, 0, 0);
}

// barrier keeping N newest vm ops (glds prefetches) in flight
#define PBAR(N) do {                                               \
    asm volatile("s_waitcnt vmcnt(" #N ")" ::: "memory");          \
    __builtin_amdgcn_s_barrier();                                  \
    asm volatile("" ::: "memory");                                 \
  } while (0)

// barrier ensuring all waves' LDS reads are done (before glds overwrite)
#define LBAR do {                                                  \
    asm volatile("s_waitcnt lgkmcnt(0)" ::: "memory");             \
    __builtin_amdgcn_s_barrier();                                  \
    asm volatile("" ::: "memory");                                 \
  } while (0)

// ---------------- weight prep ----------------
__global__ void prep_w1(const float* __restrict__ w, unsigned short* __restrict__ w1p){
  int i = blockIdx.x*256 + threadIdx.x;
  if (i >= 192*192) return;
  int k = i % 192, o = i / 192;
  int cc = k >> 3, kx = k & 7;
  unsigned short v = 0;
  if (cc < 21 && kx < 7){
    int c = cc / 7, ky = cc % 7;
    v = f2bf(w[(o*3 + c)*49 + ky*7 + kx]);
  }
  w1p[i] = v;
}
// w_s2 -> w2p[o][k], k=(ky*7+kx)*192+c, rows padded to 9472 with zeros
__global__ void prep_w2(const float* __restrict__ w, unsigned short* __restrict__ w2p){
  int i = blockIdx.x*256 + threadIdx.x;
  if (i >= 192*9472) return;
  int k = i % 9472, o = i / 9472;
  unsigned short v = 0;
  if (k < 9408){
    int g = k / 192, c = k % 192;
    int ky = g / 7, kx = g % 7;
    v = f2bf(w[((o*192 + c)*7 + ky)*7 + kx]);
  }
  w2p[i] = v;
}
// w_p -> w3p[o][k], k=(ky*3+kx)*960+c, rows padded to 8704 with zeros
__global__ void prep_w3(const float* __restrict__ w, unsigned short* __restrict__ w3p){
  int i = blockIdx.x*256 + threadIdx.x;
  if (i >= 768*8704) return;
  int k = i % 8704, o = i / 8704;
  unsigned short v = 0;
  if (k < 8640){
    int g = k / 960, c = k % 960;
    int ky = g / 3, kx = g % 3;
    v = f2bf(w[((o*960 + c)*3 + ky)*3 + kx]);
  }
  w3p[i] = v;
}
__global__ void prep_zp(unsigned int* __restrict__ zp){
  zp[threadIdx.x] = 0u;  // 256 B zero page
}

// ---------------- pad+im2col-kx: x -> xh2[b][c][iy(230)][ox(56)][kx(8)] bf16 ----------------
__global__ void pad_x2(const float* __restrict__ x, unsigned short* __restrict__ xh2){
  int idx = blockIdx.x*256 + threadIdx.x;
  if (idx >= 64*3*230*56*8) return;
  int kx = idx & 7; int t = idx >> 3;
  int ox = t % 56;  t /= 56;
  int iy = t % 230; t /= 230;      // t = b*3 + c
  int row = iy - 3;
  int col = 4*ox - 3 + kx;
  unsigned short v = 0;
  if (row >= 0 && row < 224 && col >= 0 && col < 224)
    v = f2bf(x[((size_t)t*224 + row)*224 + col]);
  xh2[idx] = v;
}

// ---------------- wavelet: per 16x16 block 2D WHT / 16 ----------------
__global__ void wavelet_kernel(const float* __restrict__ x, unsigned short* __restrict__ feat){
  int blk = blockIdx.x;
  int j = blk % 14; blk /= 14;
  int i = blk % 14; blk /= 14;
  int c = blk % 3;  int b = blk / 3;
  int t = threadIdx.x;
  int u = t >> 4, v = t & 15;
  float val = x[((size_t)(b*3 + c)*224 + (i*16 + u))*224 + (j*16 + v)];
  #pragma unroll
  for (int bit = 1; bit < 64; bit <<= 1){
    float p = __shfl_xor(val, bit);
    val = (t & bit) ? (p - val) : (val + p);
  }
  __shared__ float s[256];
  #pragma unroll
  for (int bit = 64; bit < 256; bit <<= 1){
    s[t] = val; __syncthreads();
    float p = s[t ^ bit]; __syncthreads();
    val = (t & bit) ? (p - val) : (val + p);
  }
  s[t] = val; __syncthreads();
  int k = t;
  int d1 = (k>>6)&3, d2 = (k>>4)&3, d3 = (k>>2)&3, d4 = k&3;
  int mr = (d1>>1) | ((d2>>1)<<1) | ((d3>>1)<<2) | ((d4>>1)<<3);
  int mc = (d1&1)  | ((d2&1)<<1)  | ((d3&1)<<2)  | ((d4&1)<<3);
  float outv = s[mr*16 + mc] * 0.0625f;
  feat[((size_t)((b*14 + i)*14 + j))*960 + (k*3 + c)] = f2bf(outv);
}

// ---------------- conv1: dbuf glds MFMA GEMM, BM=128 BN=64 K=192 (3 iters) ----------------
__global__ __launch_bounds__(256) void conv1_gemm(const unsigned short* __restrict__ xh2,
                                                  const unsigned short* __restrict__ w1p,
                                                  const float* __restrict__ b1,
                                                  unsigned short* __restrict__ sp1){
  __shared__ unsigned short As[2][128*64], Bs[2][64*64];
  int m0 = blockIdx.x*128, n0 = blockIdx.y*64;
  int tid = threadIdx.x, wave = tid >> 6, lane = tid & 63;
  int l16 = lane & 15, quad = lane >> 4;
  int wy = wave >> 1, wx = wave & 1;
  int r8 = lane >> 3, kb = (lane & 7) ^ r8;

  int Abase[4];
  #pragma unroll
  for (int j = 0; j < 4; j++){
    int row = wave*32 + j*8 + r8;
    int m = m0 + row;
    int ox = m % 56; int t = m / 56; int oy = t % 56; int b = t / 56;
    Abase[j] = (b*690 + 4*oy)*448 + ox*8;
  }
  const unsigned short* pB0 = w1p + (n0 + wave*16 + r8)*192 + kb*8;
  const unsigned short* pB1 = pB0 + 8*192;

  int sw = l16 & 7;
  int xo0 = ((quad    ) ^ sw)*8;
  int xo1 = ((quad + 4) ^ sw)*8;
  int aoff[4];
  #pragma unroll
  for (int mt = 0; mt < 4; mt++) aoff[mt] = (wy*64 + mt*16 + l16)*64;
  int boff0 = (wx*32 + l16)*64, boff1 = boff0 + 16*64;

  floatx4 acc[4][2];
  #pragma unroll
  for (int mt = 0; mt < 4; mt++)
    #pragma unroll
    for (int nt = 0; nt < 2; nt++) acc[mt][nt] = (floatx4){0.f,0.f,0.f,0.f};

  auto stage = [&](int i, int buf){
    int cc = i*8 + kb;
    int c = (cc*147) >> 10;
    int ky = cc - 7*c;
    int koff = (c*230 + ky)*448;
    #pragma unroll
    for (int j = 0; j < 4; j++)
      async16(xh2 + Abase[j] + koff, (void*)&As[buf][(wave*32 + j*8)*64]);
    async16(pB0 + i*64, (void*)&Bs[buf][(wave*16    )*64]);
    async16(pB1 + i*64, (void*)&Bs[buf][(wave*16 + 8)*64]);
  };

  stage(0, 0);
  __syncthreads();
  #pragma unroll
  for (int i = 0; i < 3; i++){
    int buf = i & 1;
    if (i < 2) stage(i+1, buf ^ 1);
    #pragma unroll
    for (int ks = 0; ks < 2; ks++){
      int xo = ks ? xo1 : xo0;
      short8 b0 = *(const short8*)&Bs[buf][boff0 + xo];
      short8 b1 = *(const short8*)&Bs[buf][boff1 + xo];
      #pragma unroll
      for (int mt = 0; mt < 4; mt++){
        short8 a = *(const short8*)&As[buf][aoff[mt] + xo];
        acc[mt][0] = __builtin_amdgcn_mfma_f32_16x16x32_bf16(a, b0, acc[mt][0], 0, 0, 0);
        acc[mt][1] = __builtin_amdgcn_mfma_f32_16x16x32_bf16(a, b1, acc[mt][1], 0, 0, 0);
      }
    }
    __syncthreads();
  }

  #pragma unroll
  for (int mt = 0; mt < 4; mt++){
    #pragma unroll
    for (int rg = 0; rg < 4; rg++){
      int row = wy*64 + mt*16 + quad*4 + rg;
      size_t ob = (size_t)(m0 + row)*192;
      #pragma unroll
      for (int nt = 0; nt < 2; nt++){
        int nn = n0 + wx*32 + nt*16 + l16;
        sp1[ob + nn] = f2bf(acc[mt][nt][rg] + b1[nn]);
      }
    }
  }
}

// ---------------- conv2/conv3: K-split-wave implicit-GEMM ----------------
// BM=BN=64, BK=128. Each of 4 waves owns a 32-wide k-slice and a full 64x64
// fp32 accumulator (4x4 MFMA tiles); partials reduced through LDS at the end.
// A/B tiles are read from LDS exactly once per iter -> 16.4 FLOP/LDS-byte
// (1.5x the 2x2-wave layout). Chunk-XOR swizzle keeps b128 reads conflict-free.
template<int MODE>
__global__ __launch_bounds__(256) void conv_gemm(const unsigned short* __restrict__ Ain,
                                                 const unsigned short* __restrict__ Bt,
                                                 const float* __restrict__ bias,
                                                 const float* __restrict__ pos,
                                                 const unsigned short* __restrict__ zp,
                                                 void* __restrict__ outp){
  constexpr int OH  = (MODE==2) ? 14 : 7;
  constexpr int OW  = OH;
  constexpr int IH  = (MODE==2) ? 56 : 14;
  constexpr int IW  = IH;
  constexpr int Cin = (MODE==2) ? 192 : 960;
  constexpr int KW  = (MODE==2) ? 7 : 3;
  constexpr int S   = (MODE==2) ? 4 : 2;
  constexpr int P   = (MODE==2) ? 3 : 1;
  constexpr int KP  = (MODE==2) ? 9472 : 8704;  // K padded to 128
  constexpr int NIT = KP/128;
  constexpr int MTI = (MODE==2) ? 196 : 49;
  constexpr int GRP = (MODE==2) ? 24 : 96;

  int id = blockIdx.x;
  int g = id / GRP, rem = id % GRP;
  int mtile = g*8 + (rem & 7), ntile = rem >> 3;
  if (mtile >= MTI) return;
  int m0 = mtile*64, n0 = ntile*64;

  __shared__ __align__(16) unsigned short As[2][8192];  // [64 rows][128 k], swizzled
  __shared__ __align__(16) unsigned short Bs[2][8192];
  int tid = threadIdx.x, w = tid >> 6, lane = tid & 63;
  int l16 = lane & 15, quad = lane >> 4;

  // ---- staging state: lane stages row r_j = w*16 + j*4 + quad, chunk gc_j ----
  int Abase[4], iybj[4], ixbj[4], cj[4], kyj[4], kxj[4];
  const unsigned short* Bp[4];
  #pragma unroll
  for (int j = 0; j < 4; j++){
    int r  = w*16 + j*4 + quad;
    int gc = l16 ^ (r & 15);
    int m = m0 + r;
    int ox = m % OW; int t = m / OW; int oy = t % OH; int bb = t / OH;
    iybj[j] = S*oy - P; ixbj[j] = S*ox - P;
    Abase[j] = ((bb*IH + iybj[j])*IW + ixbj[j])*Cin;
    cj[j] = gc*8; kyj[j] = 0; kxj[j] = 0;   // k = gc*8 < Cin in both modes
    Bp[j] = Bt + (size_t)(n0 + r)*KP + gc*8;
  }

  auto stage = [&](int buf){
    #pragma unroll
    for (int j = 0; j < 4; j++){
      int iy = iybj[j] + kyj[j], ix = ixbj[j] + kxj[j];
      bool ok = ((unsigned)iy < (unsigned)IH) && ((unsigned)ix < (unsigned)IW) && (kyj[j] < KW);
      const unsigned short* pa = ok
          ? (Ain + Abase[j] + (kyj[j]*IW + kxj[j])*Cin + cj[j]) : zp;
      async16(pa, (void*)&As[buf][(w*16 + j*4)*128]);
    }
    #pragma unroll
    for (int j = 0; j < 4; j++){
      async16(Bp[j], (void*)&Bs[buf][(w*16 + j*4)*128]);
      Bp[j] += 128;
    }
    #pragma unroll
    for (int j = 0; j < 4; j++){
      cj[j] += 128;
      if (cj[j] >= Cin){ cj[j] -= Cin; kxj[j]++; if (kxj[j] == KW){ kxj[j] = 0; kyj[j]++; } }
    }
  };

  // fragment read offsets (wave's k window = chunks w*4 .. w*4+3)
  int ch = ((w*4 + quad) ^ l16) * 8;
  int aoff[4], boff[4];
  #pragma unroll
  for (int mt = 0; mt < 4; mt++) aoff[mt] = (mt*16 + l16)*128 + ch;
  #pragma unroll
  for (int nt = 0; nt < 4; nt++) boff[nt] = (nt*16 + l16)*128 + ch;

  floatx4 acc[4][4];
  #pragma unroll
  for (int mt = 0; mt < 4; mt++)
    #pragma unroll
    for (int nt = 0; nt < 4; nt++) acc[mt][nt] = (floatx4){0.f,0.f,0.f,0.f};

  auto compute = [&](int buf){
    short8 af[4], bf[4];
    #pragma unroll
    for (int mt = 0; mt < 4; mt++) af[mt] = *(const short8*)&As[buf][aoff[mt]];
    #pragma unroll
    for (int nt = 0; nt < 4; nt++) bf[nt] = *(const short8*)&Bs[buf][boff[nt]];
    #pragma unroll
    for (int mt = 0; mt < 4; mt++)
      #pragma unroll
      for (int nt = 0; nt < 4; nt++)
        acc[mt][nt] = __builtin_amdgcn_mfma_f32_16x16x32_bf16(af[mt], bf[nt], acc[mt][nt], 0, 0, 0);
  };

  // depth-2 pipeline, 2 buffers, 8 glds/wave per tile.
  stage(0); stage(1);
  for (int i = 0; i < NIT - 2; i++){
    PBAR(8);            // tile i landed; tile i+1 (8 newest) in flight
    compute(i & 1);
    LBAR;               // all waves done reading buf i&1
    stage(i & 1);       // tile i+2 -> buf i&1
  }
  PBAR(8); compute(NIT & 1);
  PBAR(0); compute((NIT - 1) & 1);
  __syncthreads();

  // ---- cross-wave reduction: 4 partial 64x64 fp32 sums via LDS ----
  float* red = (w < 2) ? ((float*)As + (w << 12)) : ((float*)Bs + ((w - 2) << 12));
  #pragma unroll
  for (int mt = 0; mt < 4; mt++)
    #pragma unroll
    for (int nt = 0; nt < 4; nt++)
      #pragma unroll
      for (int rg = 0; rg < 4; rg++)
        red[(mt*16 + quad*4 + rg)*64 + nt*16 + l16] = acc[mt][nt][rg];
  __syncthreads();

  float* r0 = (float*)As;
  float* r1 = (float*)As + 4096;
  float* r2 = (float*)Bs;
  float* r3 = (float*)Bs + 4096;
  #pragma unroll
  for (int rp = 0; rp < 4; rp++){
    int row = w*16 + rp*4 + quad;
    int off = row*64 + l16*4;
    floatx4 s = *(floatx4*)&r0[off];
    s += *(floatx4*)&r1[off];
    s += *(floatx4*)&r2[off];
    s += *(floatx4*)&r3[off];
    int nn = n0 + l16*4;
    s += *(const floatx4*)&bias[nn];
    int mm = m0 + row;
    if (MODE == 2){
      uint2 pk;
      pk.x = (unsigned)f2bf(s[0]) | ((unsigned)f2bf(s[1]) << 16);
      pk.y = (unsigned)f2bf(s[2]) | ((unsigned)f2bf(s[3]) << 16);
      *(uint2*)&((unsigned short*)outp)[(size_t)mm*960 + 768 + nn] = pk;
    } else {
      int b2 = mm / 49;
      int tt = mm - b2*49;
      s += *(const floatx4*)&pos[(size_t)(1 + tt)*768 + nn];
      *(floatx4*)&((float*)outp)[((size_t)(mm + b2 + 1))*768 + nn] = s;
    }
  }
}

// ---------------- cls row ----------------
__global__ void cls_kernel(const float* __restrict__ cls, const float* __restrict__ pos,
                           float* __restrict__ out){
  int i = blockIdx.x*256 + threadIdx.x;
  if (i >= 64*768) return;
  int e = i % 768, b = i / 768;
  out[(size_t)(b*50)*768 + e] = cls[e] + pos[e];
}

extern "C" void kernel_launch(void* const* d_in, const int* in_sizes, int n_in,
                              void* d_out, int out_size, void* d_ws, size_t ws_size,
                              hipStream_t stream){
  (void)in_sizes; (void)n_in; (void)out_size;
  const float* x    = (const float*)d_in[0];
  const float* w_s1 = (const float*)d_in[1];
  const float* b_s1 = (const float*)d_in[2];
  const float* w_s2 = (const float*)d_in[3];
  const float* b_s2 = (const float*)d_in[4];
  const float* w_p  = (const float*)d_in[5];
  const float* b_p  = (const float*)d_in[6];
  const float* cls  = (const float*)d_in[7];
  const float* pos  = (const float*)d_in[8];
  float* out = (float*)d_out;

  char* ws = (char*)d_ws;
  // ws layout (bytes):
  //   w1p  bf16 [192][192]              @ 0           (73,728)
  //   sp1  bf16 NHWC [64][56][56][192]  @ 131,072     (77,070,336) end 77,201,408
  //   zp   256 B zeros                  @ 77,201,408
  //   w2p  bf16 [192][9472]             @ 77,266,944  (3,637,248)  end 80,904,192
  //   w3p  bf16 [768][8704]             @ 80,904,192  (13,369,344) end 94,273,536
  //   feat bf16 NHWC [64][14][14][960]  @ 94,273,536  (24,084,480) end 118,358,016
  //   xh2  bf16 [64][3][230][56][8] ALIASES w2p..feat (dead after conv1)
  if (ws_size < 118358016u) return;
  unsigned short* w1p  = (unsigned short*)(ws + 0);
  unsigned short* sp1  = (unsigned short*)(ws + 131072);
  unsigned short* zp   = (unsigned short*)(ws + 77201408u);
  unsigned short* w2p  = (unsigned short*)(ws + 77266944u);
  unsigned short* w3p  = (unsigned short*)(ws + 80904192u);
  unsigned short* feat = (unsigned short*)(ws + 94273536u);
  unsigned short* xh2  = (unsigned short*)(ws + 77266944u);

  prep_w1<<<(192*192 + 255)/256, 256, 0, stream>>>(w_s1, w1p);
  pad_x2<<<(64*3*230*56*8)/256, 256, 0, stream>>>(x, xh2);
  conv1_gemm<<<dim3(1568, 3), 256, 0, stream>>>(xh2, w1p, b_s1, sp1);
  prep_w2<<<(192*9472 + 255)/256, 256, 0, stream>>>(w_s2, w2p);
  prep_w3<<<(768*8704 + 255)/256, 256, 0, stream>>>(w_p, w3p);
  prep_zp<<<1, 64, 0, stream>>>((unsigned int*)zp);
  wavelet_kernel<<<64*3*14*14, 256, 0, stream>>>(x, feat);
  conv_gemm<2><<<600, 256, 0, stream>>>(sp1, w2p, b_s2, nullptr, zp, (void*)feat);
  conv_gemm<3><<<672, 256, 0, stream>>>(feat, w3p, b_p, pos, zp, (void*)out);
  cls_kernel<<<(64*768 + 255)/256, 256, 0, stream>>>(cls, pos, out);
}